// Round 1
// baseline (799.453 us; speedup 1.0000x reference)
//
#include <hip/hip_runtime.h>

// PRNNLayer: B=4096 independent sequential chains over T=2048 steps, 5 states.
// R3: split into (1) a fully-parallel precompute pass for all input-only work
// (pe, day, psnow, dm=1+em, da=1+ea -- 8 of 25 trans ops + the PET VALU chain),
// staged through the OUTPUT buffer as scratch, and (2) the serial per-chain
// loop, now carrying only state-dependent math (12 exp2 + 5 rcp per step).

#define NB 4096
#define NT 2048
#define CHUNK 8
#define NCHUNK (NT / CHUNK)  // 256

#define L2E10 14.4269504089f  // 10*log2(e)  (hv(x) = sigmoid(10x))
#define L2E    1.44269504089f

__device__ __forceinline__ float rcpf(float x) { return __builtin_amdgcn_rcpf(x); }
__device__ __forceinline__ float ex2(float a)  { return __builtin_amdgcn_exp2f(a); }
// clamped exp2 for state-threshold sigmoids whose argument can overflow fp32.
__device__ __forceinline__ float ex2c(float a) { return __builtin_amdgcn_exp2f(fminf(a, 80.0f)); }
__device__ __forceinline__ float clip1e5(float x) {
    return __builtin_amdgcn_fmed3f(x, -100000.0f, 100000.0f);
}

// ---------------- Pass 1: input-only hoisted work (full-GPU parallel) -------
// Writes {pe, day, psnow, dm, da} per (b,t) into OUT (scratch; pass 2 consumes
// each chunk one double-buffer iteration before overwriting it with results).
// 4 (b,t) elements per thread: 3 float4 in, 5 float4 out, all contiguous.
__global__ __launch_bounds__(256)
void pre_kernel(const float* __restrict__ inp, const float* __restrict__ theta,
                float* __restrict__ out) {
    const float tmin_ = theta[4] * -3.0f;
    const float tmax_ = theta[5] * 3.0f;
    const float c_sn  = -L2E10 * tmin_;
    const float c_m   =  L2E10 * tmax_;

    const size_t k = (size_t)blockIdx.x * 256 + threadIdx.x;  // 4 elems each
    const float4* i4 = (const float4*)(inp + k * 12);
    const float4 A = i4[0], Bv = i4[1], C = i4[2];
    const float P[4] = {A.x, A.w, Bv.z, C.y};
    const float T[4] = {A.y, Bv.x, Bv.w, C.z};
    const float D[4] = {A.z, Bv.y, C.x, C.w};

    float o[20];
    #pragma unroll
    for (int j = 0; j < 4; ++j) {
        const float p = P[j], tm = T[j], dl = D[j];
        // pet: one rcp for both denominators
        const float A1 = tm + 237.3f;
        const float A2 = tm + 273.2f;
        const float q  = rcpf(A1 * A2);
        const float pe = 436.98672f * dl * ex2(24.958624f * tm * (q * A2)) * (q * A1);
        const float day = rcpf(1.0f + ex2(fmaf(-L2E10, dl, 7.21347520f)));
        const float psnow = rcpf(1.0f + ex2(fmaf(L2E10, tm, c_sn))) * p;
        const float dm = 1.0f + ex2(fmaf(-L2E10, tm, c_m));  // 1+em
        const float da = 1.0f + ex2(fmaf(-L2E10, p, L2E));   // 1+ea
        o[j * 5 + 0] = pe;
        o[j * 5 + 1] = day;
        o[j * 5 + 2] = psnow;
        o[j * 5 + 3] = dm;
        o[j * 5 + 4] = da;
    }
    float4* o4 = (float4*)(out + k * 20);
    const float4* os = (const float4*)o;
    #pragma unroll
    for (int j = 0; j < 5; ++j) o4[j] = os[j];
}

// ---------------- Pass 2: serial scan, state-dependent math only ------------
__global__ __launch_bounds__(64, 1)
void prnn_kernel(const float* __restrict__ inp, const float* __restrict__ theta,
                 float* __restrict__ out) {
    const int b = blockIdx.x * 64 + threadIdx.x;

    // ---- theta (wave-uniform -> scalar regs), constant-folded ----
    const float f_     = theta[0] * 0.1f;
    const float smax_  = theta[1] * 1950.0f;
    const float qmax_  = theta[2] * 50.0f;
    const float ddf_   = theta[3] * 5.0f;
    const float tmax_  = theta[5] * 3.0f;
    const float Kc_    = theta[6] * 0.5f;
    const float SCmax_ = theta[7] * 1.5f;
    const float spmax_ = theta[8] * 1950.0f;
    const float qpmax_ = theta[9] * 40.0f;
    const float kp     = theta[10];
    const float sgmax_ = theta[11] * 1950.0f;
    const float qgmax_ = theta[12] * 40.0f;
    const float Kl_    = theta[13] * 0.5f;
    const float Kn_    = theta[14] * 0.5f;

    const float inv_smax = rcpf(smax_);
    const float KcDc  = Kc_ * 0.849932f;          // Kc_ * 0.986*0.862
    const float c_dd  = -ddf_ * tmax_;            // ddf*(tm-tmax) = fma(ddf,tm,c_dd)
    const float c_sc1 =  L2E10 * SCmax_ * 1.4f;   // zday = c_sc1*day + c_sc0
    const float c_sc0 =  L2E10 * SCmax_ * 0.6f;
    const float c_2p  =  L2E10 * spmax_;
    const float c_3s  =  L2E10 * smax_;
    const float c_4s  =  L2E10 * sgmax_;
    const float fE    = f_ * L2E;
    const float c_E2  = -fE * spmax_;
    const float c_E3  = -fE * smax_;
    const float c_E4  = -fE * sgmax_;

    const float* ip = inp + (size_t)b * (NT * 3);
    float*       op = out + (size_t)b * (NT * 5);

    float s0 = 0.f, s1 = 0.f, s2 = 0.f, s3 = 0.f, s4 = 0.f;

    float ibA[CHUNK * 3], ibB[CHUNK * 3];
    float pbA[CHUNK * 5], pbB[CHUNK * 5];

    auto prefetch = [&](float* di, float* dp, int c) {
        const float4* si = (const float4*)(ip + (size_t)c * (CHUNK * 3));
        const float4* sp = (const float4*)(op + (size_t)c * (CHUNK * 5));
        #pragma unroll
        for (int i = 0; i < (CHUNK * 3) / 4; ++i) ((float4*)di)[i] = si[i];
        #pragma unroll
        for (int i = 0; i < (CHUNK * 5) / 4; ++i) ((float4*)dp)[i] = sp[i];
    };

    auto do_chunk = [&](const float* ib, const float* pb, int c) {
        float ob[CHUNK * 5];
        #pragma unroll
        for (int s = 0; s < CHUNK; ++s) {
            const float p     = ib[s * 3 + 0];
            const float tm    = ib[s * 3 + 1];
            const float pe    = pb[s * 5 + 0];
            const float day   = pb[s * 5 + 1];
            const float psnow = pb[s * 5 + 2];
            const float dm    = pb[s * 5 + 3];
            const float da    = pb[s * 5 + 4];

            // day-derived (cheap affine/quadratic, kept in-loop to save slots)
            const float lai   = fmaf(0.328f, day, 0.15f);
            const float kcf   = fmaf(0.6f, day, 0.4f);
            const float kterm = KcDc * kcf * lai;
            const float zday  = fmaf(c_sc1, day, c_sc0);

            // pintc = R*(p + d0*esc*kterm); esc arg <= zday <= ~43 -> no clamp
            const float e0  = ex2(-L2E10 * s0);
            const float d0  = 1.0f + e0;
            const float esc = ex2(fmaf(-L2E10, s0, zday));
            const float dsc = 1.0f + esc;
            const float Rp  = rcpf(da * d0 * dsc);
            const float pintc = Rp * fmaf(d0 * esc, kterm, p);

            const float prain = p - psnow;

            // melt = rcp(dm*d1)*min(s1, ddf*(tm-tmax))
            const float e1 = ex2(-L2E10 * s1);
            const float melt = rcpf(dm * (1.0f + e1))
                               * fminf(s1, fmaf(ddf_, tm, c_dd));

            // qpref = R2*(qpmax + e2p*E2*kp*p)
            const float e2  = ex2(-L2E10 * s2);
            const float e2p = ex2c(fmaf(-L2E10, s2, c_2p));
            const float R2  = rcpf((1.0f + e2) * (1.0f + e2p));
            const float E2  = ex2(fmaf(fE, s2, c_E2));
            const float qpref = R2 * fmaf(e2p * E2, kp * p, qpmax_);

            // et+qsub+qout = R3*(pe*(1+e3s*s3/smax) + qmax*(1+e3s*E3) + (s3-smax))
            const float e3  = ex2(-L2E10 * s3);
            const float e3s = ex2c(fmaf(-L2E10, s3, c_3s));
            const float R3  = rcpf((1.0f + e3) * (1.0f + e3s));
            const float E3  = ex2(fmaf(fE, s3, c_E3));
            const float t_et = pe * fmaf(e3s * s3, inv_smax, 1.0f);
            const float t_qs = qmax_ * fmaf(e3s, E3, 1.0f);
            const float outflux = R3 * (t_et + t_qs + (s3 - smax_));
            const float ds3 = prain + melt - outflux;

            // qslow = R4*(qgmax + e4s*E4*(p*Kl + p*p*Kn))
            const float e4  = ex2(-L2E10 * s4);
            const float e4s = ex2c(fmaf(-L2E10, s4, c_4s));
            const float R4  = rcpf((1.0f + e4) * (1.0f + e4s));
            const float E4  = ex2(fmaf(fE, s4, c_E4));
            const float pl  = p * fmaf(p, Kn_, Kl_);
            const float qslow = R4 * fmaf(e4s * E4, pl, qgmax_);

            s0 += clip1e5(pintc);
            s1 += clip1e5(psnow - melt);
            s2 += clip1e5(qpref);
            s3 += clip1e5(ds3);
            s4 += clip1e5(qslow);

            ob[s * 5 + 0] = s0;
            ob[s * 5 + 1] = s1;
            ob[s * 5 + 2] = s2;
            ob[s * 5 + 3] = s3;
            ob[s * 5 + 4] = s4;
        }
        float4* dst = (float4*)(op + (size_t)c * (CHUNK * 5));
        const float4* src = (const float4*)ob;
        #pragma unroll
        for (int i = 0; i < (CHUNK * 5) / 4; ++i) dst[i] = src[i];
    };

    prefetch(ibA, pbA, 0);
    for (int c = 0; c < NCHUNK; c += 2) {
        prefetch(ibB, pbB, c + 1);
        do_chunk(ibA, pbA, c);
        if (c + 2 < NCHUNK) prefetch(ibA, pbA, c + 2);
        do_chunk(ibB, pbB, c + 1);
    }
}

extern "C" void kernel_launch(void* const* d_in, const int* in_sizes, int n_in,
                              void* d_out, int out_size, void* d_ws, size_t ws_size,
                              hipStream_t stream) {
    const float* inp   = (const float*)d_in[0];
    const float* theta = (const float*)d_in[1];
    float* out = (float*)d_out;
    // Pass 1: (NB*NT/4) threads, 4 (b,t) elements each.
    pre_kernel<<<(NB * NT / 4) / 256, 256, 0, stream>>>(inp, theta, out);
    // Pass 2: one thread per chain.
    prnn_kernel<<<NB / 64, 64, 0, stream>>>(inp, theta, out);
}